// Round 6
// baseline (3088.730 us; speedup 1.0000x reference)
//
#include <hip/hip_runtime.h>

typedef unsigned int u32;

constexpr int BATCH = 8;
constexpr int GH = 32, GW = 64;
constexpr int FH = 128, FW = 512;
constexpr int NFFT = 1024;
constexpr int HOP = 256;
constexpr int NFREQ = 513;
constexpr int NW = 512;                       // frames per batch
constexpr int SIGLEN = HOP * (NW - 1);        // 130816
constexpr int TOTAL_LEN = NFFT + HOP*(NW-1);  // 131840
constexpr int NITER = 32;
constexpr int NSAMP = 131072;
constexpr int NMAG = BATCH * NW * NFREQ;      // 2101248

// ---------------- Threefry-2x32-20, partitionable path (key = (0,1)) ----------------
__device__ __forceinline__ void tf_round(u32 &x0, u32 &x1, int r) {
  x0 += x1;
  x1 = (x1 << r) | (x1 >> (32 - r));
  x1 ^= x0;
}

__device__ __forceinline__ void threefry2(u32 c0, u32 c1, u32 &o0, u32 &o1) {
  const u32 k0 = 0u, k1 = 1u;
  const u32 k2 = 0x1BD11BDAu ^ k0 ^ k1;
  u32 x0 = c0 + k0, x1 = c1 + k1;
  tf_round(x0, x1, 13); tf_round(x0, x1, 15); tf_round(x0, x1, 26); tf_round(x0, x1, 6);
  x0 += k1; x1 += k2 + 1u;
  tf_round(x0, x1, 17); tf_round(x0, x1, 29); tf_round(x0, x1, 16); tf_round(x0, x1, 24);
  x0 += k2; x1 += k0 + 2u;
  tf_round(x0, x1, 13); tf_round(x0, x1, 15); tf_round(x0, x1, 26); tf_round(x0, x1, 6);
  x0 += k0; x1 += k1 + 3u;
  tf_round(x0, x1, 17); tf_round(x0, x1, 29); tf_round(x0, x1, 16); tf_round(x0, x1, 24);
  x0 += k1; x1 += k2 + 4u;
  tf_round(x0, x1, 13); tf_round(x0, x1, 15); tf_round(x0, x1, 26); tf_round(x0, x1, 6);
  x0 += k2; x1 += k0 + 5u;
  o0 = x0; o1 = x1;
}

// ---------------- init: win (f32 of f64 formula), win^2, wsq (f32 scatter order), tw f64 ----------------
__global__ __launch_bounds__(256) void k_init(float* __restrict__ win, float* __restrict__ win2,
                                              double2* __restrict__ tw, float* __restrict__ wsq,
                                              float2* __restrict__ tprev, u32* __restrict__ maxbuf)
{
  int idx = blockIdx.x * 256 + threadIdx.x;
  int stride = gridDim.x * 256;
  const double PI2 = 6.283185307179586476925286766559;
  for (int t = idx; t < NFFT; t += stride) {
    float w = (float)(0.5 * (1.0 - cos(PI2 * (double)t / 1024.0)));  // _WIN f32 (f64 chain, astype)
    win[t] = w;
    win2[t] = __fmul_rn(w, w);                                        // _WIN**2 in f32
  }
  for (int s = 0; s < 10; ++s) {
    int n = 1024 >> s;
    int base = 1024 - n;
    for (int p = idx; p < (n >> 1); p += stride) {
      double th = -PI2 * (double)p / (double)n;
      double2 v; v.x = cos(th); v.y = sin(th);
      tw[base + p] = v;
    }
  }
  for (int j = idx; j < TOTAL_LEN; j += stride) {
    int gmax = j >> 8; if (gmax > NW - 1) gmax = NW - 1;
    int gmin = (j >= NFFT) ? ((j - (NFFT - 1) + 255) >> 8) : 0;
    float acc = 0.f;                       // f32 scatter-add, ascending frame order (np.add.at)
    for (int g = gmin; g <= gmax; ++g) {
      float w = (float)(0.5 * (1.0 - cos(PI2 * (double)(j - (g << 8)) / 1024.0)));
      acc = __fadd_rn(acc, __fmul_rn(w, w));
    }
    wsq[j] = acc;
  }
  for (int i = idx; i < NMAG; i += stride)
    tprev[i] = make_float2(0.f, 0.f);
  if (idx < BATCH) maxbuf[idx] = 0u;
}

// ---------------- jax.image.resize bilinear, f32 weights WITH sum-normalization ----------------
__device__ __forceinline__ void lin_taps(float sf, int in, int &i0, int &i1, float &w0, float &w1)
{
  if (sf <= 0.0f)                  { i0 = 0;      i1 = 0;      w0 = 1.0f; w1 = 0.0f; return; }
  if (sf >= (float)(in - 1))       { i0 = in - 1; i1 = in - 1; w0 = 1.0f; w1 = 0.0f; return; }
  i0 = (int)sf; i1 = i0 + 1;
  float x0 = __fsub_rn(sf, (float)i0);   // exact
  float a0 = __fsub_rn(1.0f, x0);        // rounded when x0<0.5
  float S  = __fadd_rn(a0, x0);          // total_weight_sum = 1 +/- 2^-24
  w0 = __fdiv_rn(a0, S);                 // normalized (jax divides by the sum)
  w1 = __fdiv_rn(x0, S);
}

__device__ __forceinline__ float sf_H1(int H) {  // 32 -> 128, dyadic exact
  return __fadd_rn(__fmul_rn(__fadd_rn((float)H, 0.5f), 0.25f), -0.5f);
}
__device__ __forceinline__ float sf_W1(int W) {  // 64 -> 512, dyadic exact
  return __fadd_rn(__fmul_rn(__fadd_rn((float)W, 0.5f), 0.125f), -0.5f);
}
__device__ __forceinline__ float sf_H2(int K) {  // 128 -> 513, f32 inv_scale
  const float inv32 = (float)(1.0 / 4.0078125);  // f32(128/513)
  return __fadd_rn(__fmul_rn(__fadd_rn((float)K, 0.5f), inv32), -0.5f);
}

// H-contraction then W-contraction; FMA accumulation (BLAS/einsum-contract style)
__device__ __forceinline__ float fs_at(const float* __restrict__ pb, int H, int W)
{
  int r0, r1; float u0, u1;
  lin_taps(sf_H1(H), GH, r0, r1, u0, u1);
  int c0, c1; float v0, v1;
  lin_taps(sf_W1(W), GW, c0, c1, v0, v1);
  float t0 = __fmaf_rn(u1, pb[r1 * GW + c0], __fmul_rn(u0, pb[r0 * GW + c0]));
  float t1 = __fmaf_rn(u1, pb[r1 * GW + c1], __fmul_rn(u0, pb[r0 * GW + c1]));
  return __fmaf_rn(v1, t1, __fmul_rn(v0, t0));
}

__global__ __launch_bounds__(256) void k_fullspec(const float* __restrict__ p, float* __restrict__ fs)
{
  int idx = blockIdx.x * 256 + threadIdx.x;
  if (idx >= BATCH * FH * FW) return;
  int b = idx >> 16;
  int h = (idx >> 9) & (FH - 1);
  int w = idx & (FW - 1);
  fs[idx] = fs_at(p + b * (GH * GW), h, w);
}

__global__ __launch_bounds__(256) void k_mag(const float* __restrict__ p, float* __restrict__ mag)
{
  int idx = blockIdx.x * 256 + threadIdx.x;
  if (idx >= NMAG) return;
  int b = idx / (NW * NFREQ);
  int rem = idx - b * (NW * NFREQ);
  int f = rem / NFREQ;
  int k = rem - f * NFREQ;
  const float* pb = p + b * (GH * GW);
  int h0, h1; float wa, wb;
  lin_taps(sf_H2(k), FH, h0, h1, wa, wb);
  float fs0 = fs_at(pb, h0, f);
  float fs1 = fs_at(pb, h1, f);
  float P0 = __fmul_rn(__fmul_rn(fs0, fs0), 100.0f);   // full_spec**2 * 100, f32
  float P1 = __fmul_rn(__fmul_rn(fs1, fs1), 100.0f);
  float lin = __fmaf_rn(wb, P1, __fmul_rn(wa, P0));
  mag[idx] = __fsqrt_rn(fmaxf(lin, 0.0f));
}

// initial angles c64: u f32; np: exp(1j*2pi*u) -> complex64 path (weak python complex),
// theta = f32(f32(2pi)*u); cexpf ~ correctly-rounded f32 cos/sin (f64 then round).
__global__ __launch_bounds__(256) void k_phase(float2* __restrict__ ang)
{
  int idx = blockIdx.x * 256 + threadIdx.x;
  if (idx >= NMAG) return;
  int b = idx / (NW * NFREQ);
  int rem = idx - b * (NW * NFREQ);
  int f = rem / NFREQ;
  int k = rem - f * NFREQ;
  u32 cnt = (u32)(b * (NFREQ * NW) + k * NW + f);  // flat index in (B,513,512) C-order
  u32 w0, w1;
  threefry2(0u, cnt, w0, w1);
  u32 bits = w0 ^ w1;
  float u = __uint_as_float((bits >> 9) | 0x3f800000u) - 1.0f;
  float th = __fmul_rn((float)6.283185307179586, u);
  double thd = (double)th;
  ang[idx] = make_float2((float)cos(thd), (float)sin(thd));
}

// ---------------- 1024-pt complex Stockham FFT in LDS (radix-2, 10 stages, f64 internal) ----------------
template<bool INV>
__device__ __forceinline__ void fft1024d(double2* __restrict__ bufA, double2* __restrict__ bufB,
                                         const double2* __restrict__ twg, int t)
{
  double2* src = bufA;
  double2* dst = bufB;
  int n = 1024;
  for (int stage = 0; stage < 10; ++stage) {
    int m = n >> 1;
    const double2* twn = twg + (1024 - n);
    #pragma unroll
    for (int r = 0; r < 2; ++r) {
      int bi = t + (r << 8);
      int p = bi >> stage;
      int q = bi & ((1 << stage) - 1);
      double2 x0 = src[q + (p << stage)];
      double2 x1 = src[q + ((p + m) << stage)];
      double2 w = twn[p];
      double wy = INV ? -w.y : w.y;
      double2 su; su.x = x0.x + x1.x; su.y = x0.y + x1.y;
      double dx = x0.x - x1.x, dy = x0.y - x1.y;
      double2 od; od.x = dx * w.x - dy * wy; od.y = dx * wy + dy * w.x;
      dst[q + ((2 * p) << stage)]     = su;
      dst[q + ((2 * p + 1) << stage)] = od;
    }
    __syncthreads();
    double2* tmp = src; src = dst; dst = tmp;
    n >>= 1;
  }
}

// ---------------- ISTFT: frames = f32(irfft(mag_c64*ang_c64)) * win_f32 ----------------
__global__ __launch_bounds__(256) void k_istft(const float* __restrict__ mag, const float2* __restrict__ ang,
                                               float* __restrict__ frames, const double2* __restrict__ tw,
                                               const float* __restrict__ win)
{
  __shared__ double2 A[1024];
  __shared__ double2 Bq[1024];
  int bf = blockIdx.x;          // b*512 + f
  int t = threadIdx.x;
  const float*  mrow = mag + bf * NFREQ;
  const float2* arow = ang + bf * NFREQ;
  for (int k = t; k < 1024; k += 256) {
    int ks = (k <= 512) ? k : (1024 - k);
    float m = mrow[ks];
    float2 a = arow[ks];
    float Sx = __fmul_rn(m, a.x);      // c64 product (every iteration: angles stays c64 in np)
    float Sy = __fmul_rn(m, a.y);
    if (k > 512) Sy = -Sy;             // Hermitian extension (exact sign flip)
    double2 S; S.x = (double)Sx; S.y = (double)Sy;
    A[k] = S;
  }
  __syncthreads();
  fft1024d<true>(A, Bq, tw, t);        // unnormalized inverse DFT, f64
  float* frow = frames + bf * NFFT;
  for (int nn = t; nn < 1024; nn += 256) {
    float ir = (float)(A[nn].x * (1.0 / 1024.0));   // irfft output quantized to f32 (astype)
    frow[nn] = __fmul_rn(ir, win[nn]);              // * _WIN in f32
  }
}

// signal sample at sig-coordinate j: f32 scatter-order OLA + f32 division
__device__ __forceinline__ float sig_sample(const float* __restrict__ fb, const float* __restrict__ wsq, int j)
{
  int gmax = j >> 8; if (gmax > NW - 1) gmax = NW - 1;
  int gmin = (j >= NFFT) ? ((j - (NFFT - 1) + 255) >> 8) : 0;
  float acc = 0.f;
  for (int g = gmin; g <= gmax; ++g)
    acc = __fadd_rn(acc, fb[g * NFFT + (j - (g << 8))]);
  float wv = wsq[j];
  return __fdiv_rn(acc, wv > 1e-11f ? wv : 1.0f);
}

// ---------------- STFT (f32 framing, f64 FFT, f32-quantized bins) + momentum update (all f32) ----------------
__global__ __launch_bounds__(256) void k_stft(const float* __restrict__ frames, const float* __restrict__ wsq,
                                              const float* __restrict__ win, const double2* __restrict__ tw,
                                              float2* __restrict__ ang, float2* __restrict__ tprev)
{
  __shared__ double2 A[1024];
  __shared__ double2 Bq[1024];
  int bf = blockIdx.x;
  int b = bf >> 9;
  int f = bf & (NW - 1);
  int t = threadIdx.x;
  const float* fb = frames + b * (NW * NFFT);
  for (int tt = t; tt < 1024; tt += 256) {
    int m = f * HOP + tt;       // xp coordinate
    int n = m - 512;            // signal coordinate, reflect-padded
    if (n < 0) n = -n;
    if (n >= SIGLEN) n = 2 * SIGLEN - 2 - n;
    float s = sig_sample(fb, wsq, n + 512);
    double2 v; v.x = (double)__fmul_rn(s, win[tt]); v.y = 0.0;   // frame * _WIN in f32
    A[tt] = v;
  }
  __syncthreads();
  fft1024d<false>(A, Bq, tw, t);
  float2* arow = ang + bf * NFREQ;
  float2* prow = tprev + bf * NFREQ;
  const float cf = (float)(0.99 / 1.99);   // MOMENTUM/(1+MOMENTUM), weak scalar -> f32
  for (int k = t; k < NFREQ; k += 256) {
    float rx = (float)A[k].x;              // rfft output quantized to c64 (astype)
    float ry = (float)A[k].y;
    float2 pv = prow[k];
    float ax = __fsub_rn(rx, __fmul_rn(pv.x, cf));   // rebuilt - tprev*c, f32 complex ops
    float ay = __fsub_rn(ry, __fmul_rn(pv.y, cf));
    // np.abs(c64) = glibc hypotf = (float)sqrt((double)x*x + (double)y*y)
    double dx = (double)ax, dy = (double)ay;
    float d = (float)sqrt(dx * dx + dy * dy);
    float d2 = __fadd_rn(d, 1e-16f);
    // numpy c64 Smith division with real divisor: multiply by f32 reciprocal
    float inv = __fdiv_rn(1.0f, d2);
    arow[k] = make_float2(__fmul_rn(ax, inv), __fmul_rn(ay, inv));
    prow[k] = make_float2(rx, ry);
  }
}

// ---------------- final OLA -> audio f32 + per-batch |max| ----------------
__global__ __launch_bounds__(256) void k_ola(const float* __restrict__ frames, const float* __restrict__ wsq,
                                             float* __restrict__ audio, u32* __restrict__ maxbuf)
{
  int idx = blockIdx.x * 256 + threadIdx.x;  // < BATCH*NSAMP
  int b  = idx >> 17;
  int nn = idx & (NSAMP - 1);
  float v = 0.f;
  if (nn < SIGLEN)
    v = sig_sample(frames + b * (NW * NFFT), wsq, nn + 512);
  audio[idx] = v;
  __shared__ float red[256];
  red[threadIdx.x] = fabsf(v);
  __syncthreads();
  for (int s = 128; s > 0; s >>= 1) {
    if (threadIdx.x < s) red[threadIdx.x] = fmaxf(red[threadIdx.x], red[threadIdx.x + s]);
    __syncthreads();
  }
  if (threadIdx.x == 0)
    atomicMax(maxbuf + b, __float_as_uint(red[0]));  // non-negative: uint order == float order
}

__global__ __launch_bounds__(256) void k_norm(const float* __restrict__ audio, const u32* __restrict__ maxbuf,
                                              float* __restrict__ out)
{
  int idx = blockIdx.x * 256 + threadIdx.x;
  int b = idx >> 17;
  float m = fmaxf(__uint_as_float(maxbuf[b]), 1e-8f);
  out[idx] = __fmul_rn(__fdiv_rn(audio[idx], m), 0.9f);   // (audio / max_val) * 0.9, f32
}

extern "C" void kernel_launch(void* const* d_in, const int* in_sizes, int n_in,
                              void* d_out, int out_size, void* d_ws, size_t ws_size,
                              hipStream_t stream)
{
  const float* params = (const float*)d_in[0];
  float* out   = (float*)d_out;
  float* audio_out = out;                   // BATCH*NSAMP
  float* fs        = out + BATCH * NSAMP;   // BATCH*FH*FW (full_spec output)

  // workspace layout (16B-aligned first)
  double2* tw     = (double2*)d_ws;                        // 1023
  float2*  ang    = (float2*)(tw + 1023);                  // NMAG c64
  float2*  tprev  = ang + NMAG;                            // NMAG c64
  float*   frames = (float*)(tprev + NMAG);                // BATCH*NW*NFFT f32
  float*   mag    = frames + BATCH * NW * NFFT;            // NMAG f32
  float*   win    = mag + NMAG;                            // NFFT
  float*   win2   = win + NFFT;                            // NFFT
  float*   wsq    = win2 + NFFT;                           // TOTAL_LEN
  float*   audio32= wsq + TOTAL_LEN;                       // BATCH*NSAMP
  u32*     maxbuf = (u32*)(audio32 + BATCH * NSAMP);       // BATCH

  k_init<<<512, 256, 0, stream>>>(win, win2, tw, wsq, tprev, maxbuf);
  k_fullspec<<<(BATCH * FH * FW) / 256, 256, 0, stream>>>(params, fs);
  k_mag<<<(NMAG + 255) / 256, 256, 0, stream>>>(params, mag);
  k_phase<<<(NMAG + 255) / 256, 256, 0, stream>>>(ang);

  for (int it = 0; it < NITER; ++it) {
    k_istft<<<BATCH * NW, 256, 0, stream>>>(mag, (const float2*)ang, frames, tw, win);
    k_stft<<<BATCH * NW, 256, 0, stream>>>(frames, wsq, win, tw, ang, tprev);
  }
  k_istft<<<BATCH * NW, 256, 0, stream>>>(mag, (const float2*)ang, frames, tw, win);
  k_ola<<<(BATCH * NSAMP) / 256, 256, 0, stream>>>(frames, wsq, audio32, maxbuf);
  k_norm<<<(BATCH * NSAMP) / 256, 256, 0, stream>>>(audio32, maxbuf, audio_out);
}

// Round 7
// 1613.368 us; speedup vs baseline: 1.9145x; 1.9145x over previous
//
#include <hip/hip_runtime.h>

typedef unsigned int u32;

constexpr int BATCH = 8;
constexpr int GH = 32, GW = 64;
constexpr int FH = 128, FW = 512;
constexpr int NFFT = 1024;
constexpr int HOP = 256;
constexpr int NFREQ = 513;
constexpr int NW = 512;                       // frames per batch
constexpr int SIGLEN = HOP * (NW - 1);        // 130816
constexpr int TOTAL_LEN = NFFT + HOP*(NW-1);  // 131840
constexpr int NITER = 32;
constexpr int NSAMP = 131072;
constexpr int NMAG = BATCH * NW * NFREQ;      // 2101248

// ---------------- Threefry-2x32-20, partitionable path (key = (0,1)) ----------------
__device__ __forceinline__ void tf_round(u32 &x0, u32 &x1, int r) {
  x0 += x1;
  x1 = (x1 << r) | (x1 >> (32 - r));
  x1 ^= x0;
}

__device__ __forceinline__ void threefry2(u32 c0, u32 c1, u32 &o0, u32 &o1) {
  const u32 k0 = 0u, k1 = 1u;
  const u32 k2 = 0x1BD11BDAu ^ k0 ^ k1;
  u32 x0 = c0 + k0, x1 = c1 + k1;
  tf_round(x0, x1, 13); tf_round(x0, x1, 15); tf_round(x0, x1, 26); tf_round(x0, x1, 6);
  x0 += k1; x1 += k2 + 1u;
  tf_round(x0, x1, 17); tf_round(x0, x1, 29); tf_round(x0, x1, 16); tf_round(x0, x1, 24);
  x0 += k2; x1 += k0 + 2u;
  tf_round(x0, x1, 13); tf_round(x0, x1, 15); tf_round(x0, x1, 26); tf_round(x0, x1, 6);
  x0 += k0; x1 += k1 + 3u;
  tf_round(x0, x1, 17); tf_round(x0, x1, 29); tf_round(x0, x1, 16); tf_round(x0, x1, 24);
  x0 += k1; x1 += k2 + 4u;
  tf_round(x0, x1, 13); tf_round(x0, x1, 15); tf_round(x0, x1, 26); tf_round(x0, x1, 6);
  x0 += k2; x1 += k0 + 5u;
  o0 = x0; o1 = x1;
}

// ---------------- init: win f32, twiddle tables f64, wsq f32, tprev=0, maxbuf=0 ----------------
__global__ __launch_bounds__(256) void k_init(float* __restrict__ win,
                                              double2* __restrict__ tw512, double2* __restrict__ twh,
                                              float* __restrict__ wsq,
                                              float2* __restrict__ tprev, u32* __restrict__ maxbuf)
{
  int idx = blockIdx.x * 256 + threadIdx.x;
  int stride = gridDim.x * 256;
  const double PI2 = 6.283185307179586476925286766559;
  for (int t = idx; t < NFFT; t += stride)
    win[t] = (float)(0.5 * (1.0 - cos(PI2 * (double)t / 1024.0)));  // _WIN f32
  for (int k = idx; k < 512; k += stride) {
    double th = -PI2 * (double)k / 512.0;
    double2 v; v.x = cos(th); v.y = sin(th);
    tw512[k] = v;                                     // e^{-2pi i k/512}
    double th2 = -PI2 * (double)k / 1024.0;
    double2 v2; v2.x = cos(th2); v2.y = sin(th2);
    twh[k] = v2;                                      // e^{-2pi i k/1024}
  }
  for (int j = idx; j < TOTAL_LEN; j += stride) {
    int gmax = j >> 8; if (gmax > NW - 1) gmax = NW - 1;
    int gmin = (j >= NFFT) ? ((j - (NFFT - 1) + 255) >> 8) : 0;
    float acc = 0.f;                       // f32 scatter-add, ascending frame order
    for (int g = gmin; g <= gmax; ++g) {
      float w = (float)(0.5 * (1.0 - cos(PI2 * (double)(j - (g << 8)) / 1024.0)));
      acc = __fadd_rn(acc, __fmul_rn(w, w));
    }
    wsq[j] = acc;
  }
  for (int i = idx; i < NMAG; i += stride)
    tprev[i] = make_float2(0.f, 0.f);
  if (idx < BATCH) maxbuf[idx] = 0u;
}

// ---------------- jax.image.resize bilinear, f32 weights WITH sum-normalization ----------------
__device__ __forceinline__ void lin_taps(float sf, int in, int &i0, int &i1, float &w0, float &w1)
{
  if (sf <= 0.0f)                  { i0 = 0;      i1 = 0;      w0 = 1.0f; w1 = 0.0f; return; }
  if (sf >= (float)(in - 1))       { i0 = in - 1; i1 = in - 1; w0 = 1.0f; w1 = 0.0f; return; }
  i0 = (int)sf; i1 = i0 + 1;
  float x0 = __fsub_rn(sf, (float)i0);   // exact
  float a0 = __fsub_rn(1.0f, x0);
  float S  = __fadd_rn(a0, x0);          // total_weight_sum = 1 +/- 2^-24
  w0 = __fdiv_rn(a0, S);                 // normalized (jax divides by the sum)
  w1 = __fdiv_rn(x0, S);
}

__device__ __forceinline__ float sf_H1(int H) {  // 32 -> 128
  return __fadd_rn(__fmul_rn(__fadd_rn((float)H, 0.5f), 0.25f), -0.5f);
}
__device__ __forceinline__ float sf_W1(int W) {  // 64 -> 512
  return __fadd_rn(__fmul_rn(__fadd_rn((float)W, 0.5f), 0.125f), -0.5f);
}
__device__ __forceinline__ float sf_H2(int K) {  // 128 -> 513, f32 inv_scale
  const float inv32 = (float)(1.0 / 4.0078125);  // f32(128/513)
  return __fadd_rn(__fmul_rn(__fadd_rn((float)K, 0.5f), inv32), -0.5f);
}

__device__ __forceinline__ float fs_at(const float* __restrict__ pb, int H, int W)
{
  int r0, r1; float u0, u1;
  lin_taps(sf_H1(H), GH, r0, r1, u0, u1);
  int c0, c1; float v0, v1;
  lin_taps(sf_W1(W), GW, c0, c1, v0, v1);
  float t0 = __fmaf_rn(u1, pb[r1 * GW + c0], __fmul_rn(u0, pb[r0 * GW + c0]));
  float t1 = __fmaf_rn(u1, pb[r1 * GW + c1], __fmul_rn(u0, pb[r0 * GW + c1]));
  return __fmaf_rn(v1, t1, __fmul_rn(v0, t0));
}

__global__ __launch_bounds__(256) void k_fullspec(const float* __restrict__ p, float* __restrict__ fs)
{
  int idx = blockIdx.x * 256 + threadIdx.x;
  if (idx >= BATCH * FH * FW) return;
  int b = idx >> 16;
  int h = (idx >> 9) & (FH - 1);
  int w = idx & (FW - 1);
  fs[idx] = fs_at(p + b * (GH * GW), h, w);
}

__global__ __launch_bounds__(256) void k_mag(const float* __restrict__ p, float* __restrict__ mag)
{
  int idx = blockIdx.x * 256 + threadIdx.x;
  if (idx >= NMAG) return;
  int b = idx / (NW * NFREQ);
  int rem = idx - b * (NW * NFREQ);
  int f = rem / NFREQ;
  int k = rem - f * NFREQ;
  const float* pb = p + b * (GH * GW);
  int h0, h1; float wa, wb;
  lin_taps(sf_H2(k), FH, h0, h1, wa, wb);
  float fs0 = fs_at(pb, h0, f);
  float fs1 = fs_at(pb, h1, f);
  float P0 = __fmul_rn(__fmul_rn(fs0, fs0), 100.0f);
  float P1 = __fmul_rn(__fmul_rn(fs1, fs1), 100.0f);
  float lin = __fmaf_rn(wb, P1, __fmul_rn(wa, P0));
  mag[idx] = __fsqrt_rn(fmaxf(lin, 0.0f));
}

__global__ __launch_bounds__(256) void k_phase(float2* __restrict__ ang)
{
  int idx = blockIdx.x * 256 + threadIdx.x;
  if (idx >= NMAG) return;
  int b = idx / (NW * NFREQ);
  int rem = idx - b * (NW * NFREQ);
  int f = rem / NFREQ;
  int k = rem - f * NFREQ;
  u32 cnt = (u32)(b * (NFREQ * NW) + k * NW + f);  // flat index in (B,513,512) C-order
  u32 w0, w1;
  threefry2(0u, cnt, w0, w1);
  u32 bits = w0 ^ w1;
  float u = __uint_as_float((bits >> 9) | 0x3f800000u) - 1.0f;
  float th = __fmul_rn((float)6.283185307179586, u);
  double thd = (double)th;
  ang[idx] = make_float2((float)cos(thd), (float)sin(thd));
}

// ---------------- 512-pt complex FFT: 4 radix-4 Stockham stages + 1 radix-2, f64, LDS ----------------
// 128 threads; returns pointer to result buffer (natural order). Twiddle: tw512[k]=e^{-2pi i k/512}.
template<bool INV>
__device__ __forceinline__ double2* fft512d(double2* __restrict__ A, double2* __restrict__ B,
                                            const double2* __restrict__ tw512, int t)
{
  double2* src = A;
  double2* dst = B;
  #pragma unroll
  for (int s = 0; s < 4; ++s) {
    const int L = 1 << (2 * s);          // stride
    const int m = 128 >> (2 * s);        // n_s/4
    int p = t >> (2 * s);
    int q = t & (L - 1);
    double2 x0 = src[q + (p)         * L];
    double2 x1 = src[q + (p + m)     * L];
    double2 x2 = src[q + (p + 2 * m) * L];
    double2 x3 = src[q + (p + 3 * m) * L];
    double t0x = x0.x + x2.x, t0y = x0.y + x2.y;
    double t1x = x0.x - x2.x, t1y = x0.y - x2.y;
    double t2x = x1.x + x3.x, t2y = x1.y + x3.y;
    double t3x = x1.x - x3.x, t3y = x1.y - x3.y;
    double y0x = t0x + t2x, y0y = t0y + t2y;
    double y2x = t0x - t2x, y2y = t0y - t2y;
    double y1x, y1y, y3x, y3y;
    if (INV) {               // y1 = t1 + i t3 ; y3 = t1 - i t3
      y1x = t1x - t3y; y1y = t1y + t3x;
      y3x = t1x + t3y; y3y = t1y - t3x;
    } else {                 // y1 = t1 - i t3 ; y3 = t1 + i t3
      y1x = t1x + t3y; y1y = t1y - t3x;
      y3x = t1x - t3y; y3y = t1y + t3x;
    }
    int base = p << (2 * s);             // twiddle index unit: r*p*4^s
    double2 w1 = tw512[base];
    double2 w2 = tw512[2 * base];
    double2 w3 = tw512[3 * base];
    double w1y = INV ? -w1.y : w1.y;
    double w2y = INV ? -w2.y : w2.y;
    double w3y = INV ? -w3.y : w3.y;
    double2 o0; o0.x = y0x; o0.y = y0y;
    double2 o1; o1.x = y1x * w1.x - y1y * w1y; o1.y = y1x * w1y + y1y * w1.x;
    double2 o2; o2.x = y2x * w2.x - y2y * w2y; o2.y = y2x * w2y + y2y * w2.x;
    double2 o3; o3.x = y3x * w3.x - y3y * w3y; o3.y = y3x * w3y + y3y * w3.x;
    int ob = q + (4 * p) * L;
    dst[ob]         = o0;
    dst[ob + L]     = o1;
    dst[ob + 2 * L] = o2;
    dst[ob + 3 * L] = o3;
    __syncthreads();
    double2* tmp = src; src = dst; dst = tmp;
  }
  // final radix-2 stage (no twiddle): q = t and t+128
  #pragma unroll
  for (int r = 0; r < 2; ++r) {
    int q = t + (r << 7);
    double2 x0 = src[q];
    double2 x1 = src[q + 256];
    double2 e; e.x = x0.x + x1.x; e.y = x0.y + x1.y;
    double2 o; o.x = x0.x - x1.x; o.y = x0.y - x1.y;
    dst[q]       = e;
    dst[q + 256] = o;
  }
  __syncthreads();
  return dst;
}

// ---------------- ISTFT: irfft(1024) of mag*ang via ifft(512), *win, -> frames ----------------
__global__ __launch_bounds__(128) void k_istft(const float* __restrict__ mag, const float2* __restrict__ ang,
                                               float* __restrict__ frames,
                                               const double2* __restrict__ tw512,
                                               const double2* __restrict__ twh,
                                               const float* __restrict__ win)
{
  __shared__ double2 A[512];
  __shared__ double2 B[512];
  int bf = blockIdx.x;          // b*512 + f
  int t = threadIdx.x;
  const float*  mrow = mag + bf * NFREQ;
  const float2* arow = ang + bf * NFREQ;
  for (int k = t; k < 512; k += 128) {
    float m1 = mrow[k];       float2 a1 = arow[k];
    int k2 = 512 - k;
    float m2 = mrow[k2];      float2 a2 = arow[k2];
    // c64 products (np: mag_c64 * angles_c64), f32 rounding
    float S1x = __fmul_rn(m1, a1.x), S1y = __fmul_rn(m1, a1.y);
    float S2x = __fmul_rn(m2, a2.x), S2y = __fmul_rn(m2, a2.y);
    double2 Z;
    if (k == 0) {
      // DC/Nyquist: imaginary parts dropped by irfft. Z0 = (S0r+S512r)/2 + i(S0r-S512r)/2
      double e = 0.5 * ((double)S1x + (double)S2x);
      double d = 0.5 * ((double)S1x - (double)S2x);
      Z.x = e; Z.y = d;
    } else {
      // Sc = conj(S[512-k]);  Xe = (S+Sc)/2, D = (S-Sc)/2;  Z = Xe + i*conj(w^k)*D
      double Xex = 0.5 * ((double)S1x + (double)S2x);
      double Xey = 0.5 * ((double)S1y - (double)S2y);
      double Dx  = 0.5 * ((double)S1x - (double)S2x);
      double Dy  = 0.5 * ((double)S1y + (double)S2y);
      double2 w = twh[k];                  // e^{-2pi i k/1024}
      double ux = w.x * Dx + w.y * Dy;     // conj(w)*D
      double uy = w.x * Dy - w.y * Dx;
      Z.x = Xex - uy;                      // + i*u
      Z.y = Xey + ux;
    }
    A[k] = Z;
  }
  __syncthreads();
  double2* R = fft512d<true>(A, B, tw512, t);   // unnormalized inverse DFT(512)
  float* frow = frames + bf * NFFT;
  for (int m = t; m < 512; m += 128) {
    double2 z = R[m];
    float xr = (float)(z.x * (1.0 / 512.0));    // x[2m]   (f32 quantize = astype)
    float xi = (float)(z.y * (1.0 / 512.0));    // x[2m+1]
    frow[2 * m]     = __fmul_rn(xr, win[2 * m]);
    frow[2 * m + 1] = __fmul_rn(xi, win[2 * m + 1]);
  }
}

// f32 OLA sample at wsq-coordinate j
__device__ __forceinline__ float sig_sample(const float* __restrict__ fb, const float* __restrict__ wsq, int j)
{
  int gmax = j >> 8; if (gmax > NW - 1) gmax = NW - 1;
  int gmin = (j >= NFFT) ? ((j - (NFFT - 1) + 255) >> 8) : 0;
  float acc = 0.f;
  for (int g = gmin; g <= gmax; ++g)
    acc = __fadd_rn(acc, fb[g * NFFT + (j - (g << 8))]);
  float wv = wsq[j];
  return __fdiv_rn(acc, wv > 1e-11f ? wv : 1.0f);
}

// ---------------- per-iteration: OLA + reflect-pad -> xp[b][0..TOTAL_LEN) ----------------
__global__ __launch_bounds__(256) void k_sig(const float* __restrict__ frames, const float* __restrict__ wsq,
                                             float* __restrict__ xp)
{
  int idx = blockIdx.x * 256 + threadIdx.x;   // < BATCH*TOTAL_LEN
  int b = idx / TOTAL_LEN;
  int j = idx - b * TOTAL_LEN;
  int n = j - 512;
  if (n < 0) n = -n;
  if (n >= SIGLEN) n = 2 * SIGLEN - 2 - n;
  xp[idx] = sig_sample(frames + b * (NW * NFFT), wsq, n + 512);
}

// ---------------- STFT: rfft(1024) via fft(512) + momentum phase update ----------------
__global__ __launch_bounds__(128) void k_stft(const float* __restrict__ xp,
                                              const float* __restrict__ win,
                                              const double2* __restrict__ tw512,
                                              const double2* __restrict__ twh,
                                              float2* __restrict__ ang, float2* __restrict__ tprev)
{
  __shared__ double2 A[512];
  __shared__ double2 B[512];
  int bf = blockIdx.x;
  int b = bf >> 9;
  int f = bf & (NW - 1);
  int t = threadIdx.x;
  const float* xrow = xp + b * TOTAL_LEN + f * HOP;
  for (int m = t; m < 512; m += 128) {
    float s0 = __fmul_rn(xrow[2 * m],     win[2 * m]);      // frame*win in f32
    float s1 = __fmul_rn(xrow[2 * m + 1], win[2 * m + 1]);
    double2 z; z.x = (double)s0; z.y = (double)s1;
    A[m] = z;
  }
  __syncthreads();
  double2* R = fft512d<false>(A, B, tw512, t);   // forward DFT(512) of packed z
  float2* arow = ang + bf * NFREQ;
  float2* prow = tprev + bf * NFREQ;
  const float cf = (float)(0.99 / 1.99);
  for (int k = t; k < NFREQ; k += 128) {
    double rx, ry;
    if (k == 0)        { rx = R[0].x + R[0].y; ry = 0.0; }
    else if (k == 512) { rx = R[0].x - R[0].y; ry = 0.0; }
    else {
      double2 Zk = R[k];
      double2 Zc = R[512 - k];
      double Xex = 0.5 * (Zk.x + Zc.x);
      double Xey = 0.5 * (Zk.y - Zc.y);
      double Gx  = 0.5 * (Zk.x - Zc.x);
      double Gy  = 0.5 * (Zk.y + Zc.y);
      double Xox = Gy, Xoy = -Gx;          // Xo = -i*G
      double2 w = twh[k];                  // e^{-2pi i k/1024}
      rx = Xex + (w.x * Xox - w.y * Xoy);  // S = Xe + w*Xo
      ry = Xey + (w.x * Xoy + w.y * Xox);
    }
    float rxf = (float)rx, ryf = (float)ry;  // rfft quantized to c64
    float2 pv = prow[k];
    float ax = __fsub_rn(rxf, __fmul_rn(pv.x, cf));
    float ay = __fsub_rn(ryf, __fmul_rn(pv.y, cf));
    double dx = (double)ax, dy = (double)ay;
    float d = (float)sqrt(dx * dx + dy * dy);   // np.abs(c64) = hypotf
    float d2 = __fadd_rn(d, 1e-16f);
    float inv = __fdiv_rn(1.0f, d2);
    arow[k] = make_float2(__fmul_rn(ax, inv), __fmul_rn(ay, inv));
    prow[k] = make_float2(rxf, ryf);
  }
}

// ---------------- final OLA -> audio f32 + per-batch |max| ----------------
__global__ __launch_bounds__(256) void k_ola(const float* __restrict__ frames, const float* __restrict__ wsq,
                                             float* __restrict__ audio, u32* __restrict__ maxbuf)
{
  int idx = blockIdx.x * 256 + threadIdx.x;  // < BATCH*NSAMP
  int b  = idx >> 17;
  int nn = idx & (NSAMP - 1);
  float v = 0.f;
  if (nn < SIGLEN)
    v = sig_sample(frames + b * (NW * NFFT), wsq, nn + 512);
  audio[idx] = v;
  __shared__ float red[256];
  red[threadIdx.x] = fabsf(v);
  __syncthreads();
  for (int s = 128; s > 0; s >>= 1) {
    if (threadIdx.x < s) red[threadIdx.x] = fmaxf(red[threadIdx.x], red[threadIdx.x + s]);
    __syncthreads();
  }
  if (threadIdx.x == 0)
    atomicMax(maxbuf + b, __float_as_uint(red[0]));
}

__global__ __launch_bounds__(256) void k_norm(const float* __restrict__ audio, const u32* __restrict__ maxbuf,
                                              float* __restrict__ out)
{
  int idx = blockIdx.x * 256 + threadIdx.x;
  int b = idx >> 17;
  float m = fmaxf(__uint_as_float(maxbuf[b]), 1e-8f);
  out[idx] = __fmul_rn(__fdiv_rn(audio[idx], m), 0.9f);
}

extern "C" void kernel_launch(void* const* d_in, const int* in_sizes, int n_in,
                              void* d_out, int out_size, void* d_ws, size_t ws_size,
                              hipStream_t stream)
{
  const float* params = (const float*)d_in[0];
  float* out   = (float*)d_out;
  float* audio_out = out;                   // BATCH*NSAMP
  float* fs        = out + BATCH * NSAMP;   // BATCH*FH*FW (full_spec output)

  // workspace layout (16B-aligned first)
  double2* tw512  = (double2*)d_ws;                        // 512
  double2* twh    = tw512 + 512;                           // 512
  float2*  ang    = (float2*)(twh + 512);                  // NMAG c64
  float2*  tprev  = ang + NMAG;                            // NMAG c64
  float*   frames = (float*)(tprev + NMAG);                // BATCH*NW*NFFT f32
  float*   mag    = frames + BATCH * NW * NFFT;            // NMAG f32
  float*   xp     = mag + NMAG;                            // BATCH*TOTAL_LEN f32
  float*   win    = xp + BATCH * TOTAL_LEN;                // NFFT
  float*   wsq    = win + NFFT;                            // TOTAL_LEN
  float*   audio32= wsq + TOTAL_LEN;                       // BATCH*NSAMP
  u32*     maxbuf = (u32*)(audio32 + BATCH * NSAMP);       // BATCH

  k_init<<<512, 256, 0, stream>>>(win, tw512, twh, wsq, tprev, maxbuf);
  k_fullspec<<<(BATCH * FH * FW) / 256, 256, 0, stream>>>(params, fs);
  k_mag<<<(NMAG + 255) / 256, 256, 0, stream>>>(params, mag);
  k_phase<<<(NMAG + 255) / 256, 256, 0, stream>>>(ang);

  for (int it = 0; it < NITER; ++it) {
    k_istft<<<BATCH * NW, 128, 0, stream>>>(mag, (const float2*)ang, frames, tw512, twh, win);
    k_sig<<<(BATCH * TOTAL_LEN) / 256, 256, 0, stream>>>(frames, wsq, xp);
    k_stft<<<BATCH * NW, 128, 0, stream>>>(xp, win, tw512, twh, ang, tprev);
  }
  k_istft<<<BATCH * NW, 128, 0, stream>>>(mag, (const float2*)ang, frames, tw512, twh, win);
  k_ola<<<(BATCH * NSAMP) / 256, 256, 0, stream>>>(frames, wsq, audio32, maxbuf);
  k_norm<<<(BATCH * NSAMP) / 256, 256, 0, stream>>>(audio32, maxbuf, audio_out);
}

// Round 8
// 1575.703 us; speedup vs baseline: 1.9602x; 1.0239x over previous
//
#include <hip/hip_runtime.h>

typedef unsigned int u32;

constexpr int BATCH = 8;
constexpr int GH = 32, GW = 64;
constexpr int FH = 128, FW = 512;
constexpr int NFFT = 1024;
constexpr int HOP = 256;
constexpr int NFREQ = 513;
constexpr int NW = 512;                       // frames per batch
constexpr int SIGLEN = HOP * (NW - 1);        // 130816
constexpr int TOTAL_LEN = NFFT + HOP*(NW-1);  // 131840
constexpr int NITER = 32;
constexpr int NSAMP = 131072;
constexpr int NMAG = BATCH * NW * NFREQ;      // 2101248

// ---------------- Threefry-2x32-20, partitionable path (key = (0,1)) ----------------
__device__ __forceinline__ void tf_round(u32 &x0, u32 &x1, int r) {
  x0 += x1;
  x1 = (x1 << r) | (x1 >> (32 - r));
  x1 ^= x0;
}

__device__ __forceinline__ void threefry2(u32 c0, u32 c1, u32 &o0, u32 &o1) {
  const u32 k0 = 0u, k1 = 1u;
  const u32 k2 = 0x1BD11BDAu ^ k0 ^ k1;
  u32 x0 = c0 + k0, x1 = c1 + k1;
  tf_round(x0, x1, 13); tf_round(x0, x1, 15); tf_round(x0, x1, 26); tf_round(x0, x1, 6);
  x0 += k1; x1 += k2 + 1u;
  tf_round(x0, x1, 17); tf_round(x0, x1, 29); tf_round(x0, x1, 16); tf_round(x0, x1, 24);
  x0 += k2; x1 += k0 + 2u;
  tf_round(x0, x1, 13); tf_round(x0, x1, 15); tf_round(x0, x1, 26); tf_round(x0, x1, 6);
  x0 += k0; x1 += k1 + 3u;
  tf_round(x0, x1, 17); tf_round(x0, x1, 29); tf_round(x0, x1, 16); tf_round(x0, x1, 24);
  x0 += k1; x1 += k2 + 4u;
  tf_round(x0, x1, 13); tf_round(x0, x1, 15); tf_round(x0, x1, 26); tf_round(x0, x1, 6);
  x0 += k2; x1 += k0 + 5u;
  o0 = x0; o1 = x1;
}

// ---------------- init: win f32, twiddle tables f64, wsq f32, tprev=0 ----------------
__global__ __launch_bounds__(256) void k_init(float* __restrict__ win,
                                              double2* __restrict__ tw512, double2* __restrict__ twh,
                                              float* __restrict__ wsq,
                                              float2* __restrict__ tprev)
{
  int idx = blockIdx.x * 256 + threadIdx.x;
  int stride = gridDim.x * 256;
  const double PI2 = 6.283185307179586476925286766559;
  for (int t = idx; t < NFFT; t += stride)
    win[t] = (float)(0.5 * (1.0 - cos(PI2 * (double)t / 1024.0)));  // _WIN f32
  for (int k = idx; k < 512; k += stride) {
    double th = -PI2 * (double)k / 512.0;
    double2 v; v.x = cos(th); v.y = sin(th);
    tw512[k] = v;                                     // e^{-2pi i k/512}
    double th2 = -PI2 * (double)k / 1024.0;
    double2 v2; v2.x = cos(th2); v2.y = sin(th2);
    twh[k] = v2;                                      // e^{-2pi i k/1024}
  }
  for (int j = idx; j < TOTAL_LEN; j += stride) {
    int gmax = j >> 8; if (gmax > NW - 1) gmax = NW - 1;
    int gmin = (j >= NFFT) ? ((j - (NFFT - 1) + 255) >> 8) : 0;
    float acc = 0.f;                       // f32 scatter-add, ascending frame order
    for (int g = gmin; g <= gmax; ++g) {
      float w = (float)(0.5 * (1.0 - cos(PI2 * (double)(j - (g << 8)) / 1024.0)));
      acc = __fadd_rn(acc, __fmul_rn(w, w));
    }
    wsq[j] = acc;
  }
  for (int i = idx; i < NMAG; i += stride)
    tprev[i] = make_float2(0.f, 0.f);
}

// ---------------- jax.image.resize bilinear, f32 weights WITH sum-normalization ----------------
__device__ __forceinline__ void lin_taps(float sf, int in, int &i0, int &i1, float &w0, float &w1)
{
  if (sf <= 0.0f)                  { i0 = 0;      i1 = 0;      w0 = 1.0f; w1 = 0.0f; return; }
  if (sf >= (float)(in - 1))       { i0 = in - 1; i1 = in - 1; w0 = 1.0f; w1 = 0.0f; return; }
  i0 = (int)sf; i1 = i0 + 1;
  float x0 = __fsub_rn(sf, (float)i0);   // exact
  float a0 = __fsub_rn(1.0f, x0);
  float S  = __fadd_rn(a0, x0);          // total_weight_sum = 1 +/- 2^-24
  w0 = __fdiv_rn(a0, S);                 // normalized (jax divides by the sum)
  w1 = __fdiv_rn(x0, S);
}

__device__ __forceinline__ float sf_H1(int H) {  // 32 -> 128
  return __fadd_rn(__fmul_rn(__fadd_rn((float)H, 0.5f), 0.25f), -0.5f);
}
__device__ __forceinline__ float sf_W1(int W) {  // 64 -> 512
  return __fadd_rn(__fmul_rn(__fadd_rn((float)W, 0.5f), 0.125f), -0.5f);
}
__device__ __forceinline__ float sf_H2(int K) {  // 128 -> 513, f32 inv_scale
  const float inv32 = (float)(1.0 / 4.0078125);  // f32(128/513)
  return __fadd_rn(__fmul_rn(__fadd_rn((float)K, 0.5f), inv32), -0.5f);
}

__device__ __forceinline__ float fs_at(const float* __restrict__ pb, int H, int W)
{
  int r0, r1; float u0, u1;
  lin_taps(sf_H1(H), GH, r0, r1, u0, u1);
  int c0, c1; float v0, v1;
  lin_taps(sf_W1(W), GW, c0, c1, v0, v1);
  float t0 = __fmaf_rn(u1, pb[r1 * GW + c0], __fmul_rn(u0, pb[r0 * GW + c0]));
  float t1 = __fmaf_rn(u1, pb[r1 * GW + c1], __fmul_rn(u0, pb[r0 * GW + c1]));
  return __fmaf_rn(v1, t1, __fmul_rn(v0, t0));
}

__global__ __launch_bounds__(256) void k_fullspec(const float* __restrict__ p, float* __restrict__ fs)
{
  int idx = blockIdx.x * 256 + threadIdx.x;
  if (idx >= BATCH * FH * FW) return;
  int b = idx >> 16;
  int h = (idx >> 9) & (FH - 1);
  int w = idx & (FW - 1);
  fs[idx] = fs_at(p + b * (GH * GW), h, w);
}

__global__ __launch_bounds__(256) void k_mag(const float* __restrict__ p, float* __restrict__ mag)
{
  int idx = blockIdx.x * 256 + threadIdx.x;
  if (idx >= NMAG) return;
  int b = idx / (NW * NFREQ);
  int rem = idx - b * (NW * NFREQ);
  int f = rem / NFREQ;
  int k = rem - f * NFREQ;
  const float* pb = p + b * (GH * GW);
  int h0, h1; float wa, wb;
  lin_taps(sf_H2(k), FH, h0, h1, wa, wb);
  float fs0 = fs_at(pb, h0, f);
  float fs1 = fs_at(pb, h1, f);
  float P0 = __fmul_rn(__fmul_rn(fs0, fs0), 100.0f);
  float P1 = __fmul_rn(__fmul_rn(fs1, fs1), 100.0f);
  float lin = __fmaf_rn(wb, P1, __fmul_rn(wa, P0));
  mag[idx] = __fsqrt_rn(fmaxf(lin, 0.0f));
}

__global__ __launch_bounds__(256) void k_phase(float2* __restrict__ ang)
{
  int idx = blockIdx.x * 256 + threadIdx.x;
  if (idx >= NMAG) return;
  int b = idx / (NW * NFREQ);
  int rem = idx - b * (NW * NFREQ);
  int f = rem / NFREQ;
  int k = rem - f * NFREQ;
  u32 cnt = (u32)(b * (NFREQ * NW) + k * NW + f);  // flat index in (B,513,512) C-order
  u32 w0, w1;
  threefry2(0u, cnt, w0, w1);
  u32 bits = w0 ^ w1;
  float u = __uint_as_float((bits >> 9) | 0x3f800000u) - 1.0f;
  float th = __fmul_rn((float)6.283185307179586, u);
  double thd = (double)th;
  ang[idx] = make_float2((float)cos(thd), (float)sin(thd));
}

// ---------------- 512-pt complex FFT: 4 radix-4 Stockham stages + 1 radix-2, f64, LDS ----------------
// 128 threads; result in returned buffer (natural order). Forward result lands in B, A is free.
template<bool INV>
__device__ __forceinline__ double2* fft512d(double2* __restrict__ A, double2* __restrict__ B,
                                            const double2* __restrict__ tw512, int t)
{
  double2* src = A;
  double2* dst = B;
  #pragma unroll
  for (int s = 0; s < 4; ++s) {
    const int L = 1 << (2 * s);          // stride
    const int m = 128 >> (2 * s);        // n_s/4
    int p = t >> (2 * s);
    int q = t & (L - 1);
    double2 x0 = src[q + (p)         * L];
    double2 x1 = src[q + (p + m)     * L];
    double2 x2 = src[q + (p + 2 * m) * L];
    double2 x3 = src[q + (p + 3 * m) * L];
    double t0x = x0.x + x2.x, t0y = x0.y + x2.y;
    double t1x = x0.x - x2.x, t1y = x0.y - x2.y;
    double t2x = x1.x + x3.x, t2y = x1.y + x3.y;
    double t3x = x1.x - x3.x, t3y = x1.y - x3.y;
    double y0x = t0x + t2x, y0y = t0y + t2y;
    double y2x = t0x - t2x, y2y = t0y - t2y;
    double y1x, y1y, y3x, y3y;
    if (INV) {               // y1 = t1 + i t3 ; y3 = t1 - i t3
      y1x = t1x - t3y; y1y = t1y + t3x;
      y3x = t1x + t3y; y3y = t1y - t3x;
    } else {                 // y1 = t1 - i t3 ; y3 = t1 + i t3
      y1x = t1x + t3y; y1y = t1y - t3x;
      y3x = t1x - t3y; y3y = t1y + t3x;
    }
    int base = p << (2 * s);             // twiddle index unit: r*p*4^s
    double2 w1 = tw512[base];
    double2 w2 = tw512[2 * base];
    double2 w3 = tw512[3 * base];
    double w1y = INV ? -w1.y : w1.y;
    double w2y = INV ? -w2.y : w2.y;
    double w3y = INV ? -w3.y : w3.y;
    double2 o0; o0.x = y0x; o0.y = y0y;
    double2 o1; o1.x = y1x * w1.x - y1y * w1y; o1.y = y1x * w1y + y1y * w1.x;
    double2 o2; o2.x = y2x * w2.x - y2y * w2y; o2.y = y2x * w2y + y2y * w2.x;
    double2 o3; o3.x = y3x * w3.x - y3y * w3y; o3.y = y3x * w3y + y3y * w3.x;
    int ob = q + (4 * p) * L;
    dst[ob]         = o0;
    dst[ob + L]     = o1;
    dst[ob + 2 * L] = o2;
    dst[ob + 3 * L] = o3;
    __syncthreads();
    double2* tmp = src; src = dst; dst = tmp;
  }
  // final radix-2 stage (no twiddle)
  #pragma unroll
  for (int r = 0; r < 2; ++r) {
    int q = t + (r << 7);
    double2 x0 = src[q];
    double2 x1 = src[q + 256];
    double2 e; e.x = x0.x + x1.x; e.y = x0.y + x1.y;
    double2 o; o.x = x0.x - x1.x; o.y = x0.y - x1.y;
    dst[q]       = e;
    dst[q + 256] = o;
  }
  __syncthreads();
  return dst;
}

// ---------------- initial ISTFT: irfft(1024) of mag*ang(global) via ifft(512), *win ----------------
__global__ __launch_bounds__(128) void k_istft(const float* __restrict__ mag, const float2* __restrict__ ang,
                                               float* __restrict__ frames,
                                               const double2* __restrict__ tw512,
                                               const double2* __restrict__ twh,
                                               const float* __restrict__ win)
{
  __shared__ double2 A[512];
  __shared__ double2 B[512];
  int bf = blockIdx.x;          // b*512 + f
  int t = threadIdx.x;
  const float*  mrow = mag + bf * NFREQ;
  const float2* arow = ang + bf * NFREQ;
  for (int k = t; k < 512; k += 128) {
    float m1 = mrow[k];       float2 a1 = arow[k];
    int k2 = 512 - k;
    float m2 = mrow[k2];      float2 a2 = arow[k2];
    float S1x = __fmul_rn(m1, a1.x), S1y = __fmul_rn(m1, a1.y);
    float S2x = __fmul_rn(m2, a2.x), S2y = __fmul_rn(m2, a2.y);
    double2 Z;
    if (k == 0) {
      double e = 0.5 * ((double)S1x + (double)S2x);
      double d = 0.5 * ((double)S1x - (double)S2x);
      Z.x = e; Z.y = d;
    } else {
      double Xex = 0.5 * ((double)S1x + (double)S2x);
      double Xey = 0.5 * ((double)S1y - (double)S2y);
      double Dx  = 0.5 * ((double)S1x - (double)S2x);
      double Dy  = 0.5 * ((double)S1y + (double)S2y);
      double2 w = twh[k];                  // e^{-2pi i k/1024}
      double ux = w.x * Dx + w.y * Dy;     // conj(w)*D
      double uy = w.x * Dy - w.y * Dx;
      Z.x = Xex - uy;
      Z.y = Xey + ux;
    }
    A[k] = Z;
  }
  __syncthreads();
  double2* R = fft512d<true>(A, B, tw512, t);
  float* frow = frames + bf * NFFT;
  for (int m = t; m < 512; m += 128) {
    double2 z = R[m];
    float xr = (float)(z.x * (1.0 / 512.0));
    float xi = (float)(z.y * (1.0 / 512.0));
    frow[2 * m]     = __fmul_rn(xr, win[2 * m]);
    frow[2 * m + 1] = __fmul_rn(xi, win[2 * m + 1]);
  }
}

// f32 OLA sample at wsq-coordinate j
__device__ __forceinline__ float sig_sample(const float* __restrict__ fb, const float* __restrict__ wsq, int j)
{
  int gmax = j >> 8; if (gmax > NW - 1) gmax = NW - 1;
  int gmin = (j >= NFFT) ? ((j - (NFFT - 1) + 255) >> 8) : 0;
  float acc = 0.f;
  for (int g = gmin; g <= gmax; ++g)
    acc = __fadd_rn(acc, fb[g * NFFT + (j - (g << 8))]);
  float wv = wsq[j];
  return __fdiv_rn(acc, wv > 1e-11f ? wv : 1.0f);
}

// ---------------- per-iteration: OLA + reflect-pad -> xp[b][0..TOTAL_LEN) ----------------
__global__ __launch_bounds__(256) void k_sig(const float* __restrict__ frames, const float* __restrict__ wsq,
                                             float* __restrict__ xp)
{
  int idx = blockIdx.x * 256 + threadIdx.x;   // < BATCH*TOTAL_LEN
  int b = idx / TOTAL_LEN;
  int j = idx - b * TOTAL_LEN;
  int n = j - 512;
  if (n < 0) n = -n;
  if (n >= SIGLEN) n = 2 * SIGLEN - 2 - n;
  xp[idx] = sig_sample(frames + b * (NW * NFFT), wsq, n + 512);
}

// ---------------- FUSED: stft_it (+ phase update in LDS) + istft_{it+1} ----------------
// Per frame row bf: forward rfft of windowed xp -> update ang row (LDS) + tprev (global)
// -> inverse irfft of mag*ang -> windowed frames. ang never round-trips through HBM.
__global__ __launch_bounds__(128) void k_fused(const float* __restrict__ xp,
                                               const float* __restrict__ win,
                                               const double2* __restrict__ tw512,
                                               const double2* __restrict__ twh,
                                               const float* __restrict__ mag,
                                               float2* __restrict__ tprev,
                                               float* __restrict__ frames)
{
  __shared__ double2 A[512];
  __shared__ double2 B[512];
  __shared__ float2 angL[NFREQ];
  int bf = blockIdx.x;
  int b = bf >> 9;
  int f = bf & (NW - 1);
  int t = threadIdx.x;

  // ---- forward: pack two real samples per complex point ----
  const float* xrow = xp + b * TOTAL_LEN + f * HOP;
  for (int m = t; m < 512; m += 128) {
    float s0 = __fmul_rn(xrow[2 * m],     win[2 * m]);
    float s1 = __fmul_rn(xrow[2 * m + 1], win[2 * m + 1]);
    double2 z; z.x = (double)s0; z.y = (double)s1;
    A[m] = z;
  }
  __syncthreads();
  double2* R = fft512d<false>(A, B, tw512, t);   // result in B; A free

  // ---- unpack rfft bins + momentum phase update (all f32 boundary ops) ----
  float2* prow = tprev + bf * NFREQ;
  const float cf = (float)(0.99 / 1.99);
  for (int k = t; k < NFREQ; k += 128) {
    double rx, ry;
    if (k == 0)        { rx = R[0].x + R[0].y; ry = 0.0; }
    else if (k == 512) { rx = R[0].x - R[0].y; ry = 0.0; }
    else {
      double2 Zk = R[k];
      double2 Zc = R[512 - k];
      double Xex = 0.5 * (Zk.x + Zc.x);
      double Xey = 0.5 * (Zk.y - Zc.y);
      double Gx  = 0.5 * (Zk.x - Zc.x);
      double Gy  = 0.5 * (Zk.y + Zc.y);
      double Xox = Gy, Xoy = -Gx;          // Xo = -i*G
      double2 w = twh[k];
      rx = Xex + (w.x * Xox - w.y * Xoy);
      ry = Xey + (w.x * Xoy + w.y * Xox);
    }
    float rxf = (float)rx, ryf = (float)ry;  // rfft quantized to c64
    float2 pv = prow[k];
    float ax = __fsub_rn(rxf, __fmul_rn(pv.x, cf));
    float ay = __fsub_rn(ryf, __fmul_rn(pv.y, cf));
    double dx = (double)ax, dy = (double)ay;
    float d = (float)sqrt(dx * dx + dy * dy);   // np.abs(c64) = hypotf
    float d2 = __fadd_rn(d, 1e-16f);
    float inv = __fdiv_rn(1.0f, d2);
    angL[k] = make_float2(__fmul_rn(ax, inv), __fmul_rn(ay, inv));
    prow[k] = make_float2(rxf, ryf);
  }
  __syncthreads();   // angL complete (Z build reads angL[512-k] across threads)

  // ---- inverse: Hermitian pack mag*angL into A (B still holds R; not read) ----
  const float* mrow = mag + bf * NFREQ;
  for (int k = t; k < 512; k += 128) {
    float m1 = mrow[k];       float2 a1 = angL[k];
    int k2 = 512 - k;
    float m2 = mrow[k2];      float2 a2 = angL[k2];
    float S1x = __fmul_rn(m1, a1.x), S1y = __fmul_rn(m1, a1.y);
    float S2x = __fmul_rn(m2, a2.x), S2y = __fmul_rn(m2, a2.y);
    double2 Z;
    if (k == 0) {
      double e = 0.5 * ((double)S1x + (double)S2x);
      double d = 0.5 * ((double)S1x - (double)S2x);
      Z.x = e; Z.y = d;
    } else {
      double Xex = 0.5 * ((double)S1x + (double)S2x);
      double Xey = 0.5 * ((double)S1y - (double)S2y);
      double Dx  = 0.5 * ((double)S1x - (double)S2x);
      double Dy  = 0.5 * ((double)S1y + (double)S2y);
      double2 w = twh[k];
      double ux = w.x * Dx + w.y * Dy;
      double uy = w.x * Dy - w.y * Dx;
      Z.x = Xex - uy;
      Z.y = Xey + ux;
    }
    A[k] = Z;
  }
  __syncthreads();
  double2* R2 = fft512d<true>(A, B, tw512, t);
  float* frow = frames + bf * NFFT;
  for (int m = t; m < 512; m += 128) {
    double2 z = R2[m];
    float xr = (float)(z.x * (1.0 / 512.0));
    float xi = (float)(z.y * (1.0 / 512.0));
    frow[2 * m]     = __fmul_rn(xr, win[2 * m]);
    frow[2 * m + 1] = __fmul_rn(xi, win[2 * m + 1]);
  }
}

// ---------------- final OLA -> audio f32 (pure streaming, no reduction) ----------------
__global__ __launch_bounds__(256) void k_ola(const float* __restrict__ frames, const float* __restrict__ wsq,
                                             float* __restrict__ audio)
{
  int idx = blockIdx.x * 256 + threadIdx.x;  // < BATCH*NSAMP
  int b  = idx >> 17;
  int nn = idx & (NSAMP - 1);
  float v = 0.f;
  if (nn < SIGLEN)
    v = sig_sample(frames + b * (NW * NFFT), wsq, nn + 512);
  audio[idx] = v;
}

// ---------------- per-batch |max|: one block per batch, no atomics ----------------
__global__ __launch_bounds__(256) void k_max(const float* __restrict__ audio, float* __restrict__ maxbuf)
{
  int b = blockIdx.x;
  const float* arow = audio + b * NSAMP;
  float m = 0.f;
  for (int i = threadIdx.x; i < NSAMP; i += 256)
    m = fmaxf(m, fabsf(arow[i]));
  __shared__ float red[256];
  red[threadIdx.x] = m;
  __syncthreads();
  for (int s = 128; s > 0; s >>= 1) {
    if (threadIdx.x < s) red[threadIdx.x] = fmaxf(red[threadIdx.x], red[threadIdx.x + s]);
    __syncthreads();
  }
  if (threadIdx.x == 0) maxbuf[b] = red[0];
}

__global__ __launch_bounds__(256) void k_norm(const float* __restrict__ audio, const float* __restrict__ maxbuf,
                                              float* __restrict__ out)
{
  int idx = blockIdx.x * 256 + threadIdx.x;
  int b = idx >> 17;
  float m = fmaxf(maxbuf[b], 1e-8f);
  out[idx] = __fmul_rn(__fdiv_rn(audio[idx], m), 0.9f);
}

extern "C" void kernel_launch(void* const* d_in, const int* in_sizes, int n_in,
                              void* d_out, int out_size, void* d_ws, size_t ws_size,
                              hipStream_t stream)
{
  const float* params = (const float*)d_in[0];
  float* out   = (float*)d_out;
  float* audio_out = out;                   // BATCH*NSAMP
  float* fs        = out + BATCH * NSAMP;   // BATCH*FH*FW (full_spec output)

  // workspace layout (16B-aligned first)
  double2* tw512  = (double2*)d_ws;                        // 512
  double2* twh    = tw512 + 512;                           // 512
  float2*  ang    = (float2*)(twh + 512);                  // NMAG c64 (initial phases only)
  float2*  tprev  = ang + NMAG;                            // NMAG c64
  float*   frames = (float*)(tprev + NMAG);                // BATCH*NW*NFFT f32
  float*   mag    = frames + BATCH * NW * NFFT;            // NMAG f32
  float*   xp     = mag + NMAG;                            // BATCH*TOTAL_LEN f32
  float*   win    = xp + BATCH * TOTAL_LEN;                // NFFT
  float*   wsq    = win + NFFT;                            // TOTAL_LEN
  float*   audio32= wsq + TOTAL_LEN;                       // BATCH*NSAMP
  float*   maxbuf = audio32 + BATCH * NSAMP;               // BATCH

  k_init<<<512, 256, 0, stream>>>(win, tw512, twh, wsq, tprev);
  k_fullspec<<<(BATCH * FH * FW) / 256, 256, 0, stream>>>(params, fs);
  k_mag<<<(NMAG + 255) / 256, 256, 0, stream>>>(params, mag);
  k_phase<<<(NMAG + 255) / 256, 256, 0, stream>>>(ang);

  // istft0 with initial phases, then 32x [OLA->xp ; fused stft+update+istft]
  k_istft<<<BATCH * NW, 128, 0, stream>>>(mag, (const float2*)ang, frames, tw512, twh, win);
  for (int it = 0; it < NITER; ++it) {
    k_sig<<<(BATCH * TOTAL_LEN) / 256, 256, 0, stream>>>(frames, wsq, xp);
    k_fused<<<BATCH * NW, 128, 0, stream>>>(xp, win, tw512, twh, mag, tprev, frames);
  }
  k_ola<<<(BATCH * NSAMP) / 256, 256, 0, stream>>>(frames, wsq, audio32);
  k_max<<<BATCH, 256, 0, stream>>>(audio32, maxbuf);
  k_norm<<<(BATCH * NSAMP) / 256, 256, 0, stream>>>(audio32, maxbuf, audio_out);
}

// Round 9
// 1490.248 us; speedup vs baseline: 2.0726x; 1.0573x over previous
//
#include <hip/hip_runtime.h>

typedef unsigned int u32;

constexpr int BATCH = 8;
constexpr int GH = 32, GW = 64;
constexpr int FH = 128, FW = 512;
constexpr int NFFT = 1024;
constexpr int HOP = 256;
constexpr int NFREQ = 513;
constexpr int NW = 512;                       // frames per batch
constexpr int SIGLEN = HOP * (NW - 1);        // 130816
constexpr int TOTAL_LEN = NFFT + HOP*(NW-1);  // 131840
constexpr int NITER = 32;
constexpr int NSAMP = 131072;
constexpr int NMAG = BATCH * NW * NFREQ;      // 2101248

// LDS anti-bank-conflict padding: 9/8 stride (verified: consecutive AND stride-4
// double2 b128 accesses both become minimal/conflict-free)
#define SL(i) ((i) + ((i) >> 3))
constexpr int LDSN = 512 + 64;                // 576 slots

// ---------------- Threefry-2x32-20, partitionable path (key = (0,1)) ----------------
__device__ __forceinline__ void tf_round(u32 &x0, u32 &x1, int r) {
  x0 += x1;
  x1 = (x1 << r) | (x1 >> (32 - r));
  x1 ^= x0;
}

__device__ __forceinline__ void threefry2(u32 c0, u32 c1, u32 &o0, u32 &o1) {
  const u32 k0 = 0u, k1 = 1u;
  const u32 k2 = 0x1BD11BDAu ^ k0 ^ k1;
  u32 x0 = c0 + k0, x1 = c1 + k1;
  tf_round(x0, x1, 13); tf_round(x0, x1, 15); tf_round(x0, x1, 26); tf_round(x0, x1, 6);
  x0 += k1; x1 += k2 + 1u;
  tf_round(x0, x1, 17); tf_round(x0, x1, 29); tf_round(x0, x1, 16); tf_round(x0, x1, 24);
  x0 += k2; x1 += k0 + 2u;
  tf_round(x0, x1, 13); tf_round(x0, x1, 15); tf_round(x0, x1, 26); tf_round(x0, x1, 6);
  x0 += k0; x1 += k1 + 3u;
  tf_round(x0, x1, 17); tf_round(x0, x1, 29); tf_round(x0, x1, 16); tf_round(x0, x1, 24);
  x0 += k1; x1 += k2 + 4u;
  tf_round(x0, x1, 13); tf_round(x0, x1, 15); tf_round(x0, x1, 26); tf_round(x0, x1, 6);
  x0 += k2; x1 += k0 + 5u;
  o0 = x0; o1 = x1;
}

// ---------------- init: win f32, twiddle tables f64, wsq f32, tprev=0 ----------------
__global__ __launch_bounds__(256) void k_init(float* __restrict__ win,
                                              double2* __restrict__ tw512, double2* __restrict__ twh,
                                              float* __restrict__ wsq,
                                              float2* __restrict__ tprev)
{
  int idx = blockIdx.x * 256 + threadIdx.x;
  int stride = gridDim.x * 256;
  const double PI2 = 6.283185307179586476925286766559;
  for (int t = idx; t < NFFT; t += stride)
    win[t] = (float)(0.5 * (1.0 - cos(PI2 * (double)t / 1024.0)));  // _WIN f32
  for (int k = idx; k < 512; k += stride) {
    double th = -PI2 * (double)k / 512.0;
    double2 v; v.x = cos(th); v.y = sin(th);
    tw512[k] = v;                                     // e^{-2pi i k/512}
    double th2 = -PI2 * (double)k / 1024.0;
    double2 v2; v2.x = cos(th2); v2.y = sin(th2);
    twh[k] = v2;                                      // e^{-2pi i k/1024}
  }
  for (int j = idx; j < TOTAL_LEN; j += stride) {
    int gmax = j >> 8; if (gmax > NW - 1) gmax = NW - 1;
    int gmin = (j >= NFFT) ? ((j - (NFFT - 1) + 255) >> 8) : 0;
    float acc = 0.f;                       // f32 scatter-add, ascending frame order
    for (int g = gmin; g <= gmax; ++g) {
      float w = (float)(0.5 * (1.0 - cos(PI2 * (double)(j - (g << 8)) / 1024.0)));
      acc = __fadd_rn(acc, __fmul_rn(w, w));
    }
    wsq[j] = acc;
  }
  for (int i = idx; i < NMAG; i += stride)
    tprev[i] = make_float2(0.f, 0.f);
}

// ---------------- jax.image.resize bilinear, f32 weights WITH sum-normalization ----------------
__device__ __forceinline__ void lin_taps(float sf, int in, int &i0, int &i1, float &w0, float &w1)
{
  if (sf <= 0.0f)                  { i0 = 0;      i1 = 0;      w0 = 1.0f; w1 = 0.0f; return; }
  if (sf >= (float)(in - 1))       { i0 = in - 1; i1 = in - 1; w0 = 1.0f; w1 = 0.0f; return; }
  i0 = (int)sf; i1 = i0 + 1;
  float x0 = __fsub_rn(sf, (float)i0);   // exact
  float a0 = __fsub_rn(1.0f, x0);
  float S  = __fadd_rn(a0, x0);          // total_weight_sum = 1 +/- 2^-24
  w0 = __fdiv_rn(a0, S);                 // normalized (jax divides by the sum)
  w1 = __fdiv_rn(x0, S);
}

__device__ __forceinline__ float sf_H1(int H) {  // 32 -> 128
  return __fadd_rn(__fmul_rn(__fadd_rn((float)H, 0.5f), 0.25f), -0.5f);
}
__device__ __forceinline__ float sf_W1(int W) {  // 64 -> 512
  return __fadd_rn(__fmul_rn(__fadd_rn((float)W, 0.5f), 0.125f), -0.5f);
}
__device__ __forceinline__ float sf_H2(int K) {  // 128 -> 513, f32 inv_scale
  const float inv32 = (float)(1.0 / 4.0078125);  // f32(128/513)
  return __fadd_rn(__fmul_rn(__fadd_rn((float)K, 0.5f), inv32), -0.5f);
}

__device__ __forceinline__ float fs_at(const float* __restrict__ pb, int H, int W)
{
  int r0, r1; float u0, u1;
  lin_taps(sf_H1(H), GH, r0, r1, u0, u1);
  int c0, c1; float v0, v1;
  lin_taps(sf_W1(W), GW, c0, c1, v0, v1);
  float t0 = __fmaf_rn(u1, pb[r1 * GW + c0], __fmul_rn(u0, pb[r0 * GW + c0]));
  float t1 = __fmaf_rn(u1, pb[r1 * GW + c1], __fmul_rn(u0, pb[r0 * GW + c1]));
  return __fmaf_rn(v1, t1, __fmul_rn(v0, t0));
}

__global__ __launch_bounds__(256) void k_fullspec(const float* __restrict__ p, float* __restrict__ fs)
{
  int idx = blockIdx.x * 256 + threadIdx.x;
  if (idx >= BATCH * FH * FW) return;
  int b = idx >> 16;
  int h = (idx >> 9) & (FH - 1);
  int w = idx & (FW - 1);
  fs[idx] = fs_at(p + b * (GH * GW), h, w);
}

__global__ __launch_bounds__(256) void k_mag(const float* __restrict__ p, float* __restrict__ mag)
{
  int idx = blockIdx.x * 256 + threadIdx.x;
  if (idx >= NMAG) return;
  int b = idx / (NW * NFREQ);
  int rem = idx - b * (NW * NFREQ);
  int f = rem / NFREQ;
  int k = rem - f * NFREQ;
  const float* pb = p + b * (GH * GW);
  int h0, h1; float wa, wb;
  lin_taps(sf_H2(k), FH, h0, h1, wa, wb);
  float fs0 = fs_at(pb, h0, f);
  float fs1 = fs_at(pb, h1, f);
  float P0 = __fmul_rn(__fmul_rn(fs0, fs0), 100.0f);
  float P1 = __fmul_rn(__fmul_rn(fs1, fs1), 100.0f);
  float lin = __fmaf_rn(wb, P1, __fmul_rn(wa, P0));
  mag[idx] = __fsqrt_rn(fmaxf(lin, 0.0f));
}

__global__ __launch_bounds__(256) void k_phase(float2* __restrict__ ang)
{
  int idx = blockIdx.x * 256 + threadIdx.x;
  if (idx >= NMAG) return;
  int b = idx / (NW * NFREQ);
  int rem = idx - b * (NW * NFREQ);
  int f = rem / NFREQ;
  int k = rem - f * NFREQ;
  u32 cnt = (u32)(b * (NFREQ * NW) + k * NW + f);  // flat index in (B,513,512) C-order
  u32 w0, w1;
  threefry2(0u, cnt, w0, w1);
  u32 bits = w0 ^ w1;
  float u = __uint_as_float((bits >> 9) | 0x3f800000u) - 1.0f;
  float th = __fmul_rn((float)6.283185307179586, u);
  double thd = (double)th;
  ang[idx] = make_float2((float)cos(thd), (float)sin(thd));
}

// ---------------- 512-pt complex FFT: 4 radix-4 Stockham stages + 1 radix-2, f64, LDS ----------------
// 128 threads; indices into A/B are PADDED via SL(). Result in returned buffer (B).
template<bool INV>
__device__ __forceinline__ double2* fft512d(double2* __restrict__ A, double2* __restrict__ B,
                                            const double2* __restrict__ tw512, int t)
{
  double2* src = A;
  double2* dst = B;
  #pragma unroll
  for (int s = 0; s < 4; ++s) {
    const int L = 1 << (2 * s);          // stride
    const int m = 128 >> (2 * s);        // n_s/4
    int p = t >> (2 * s);
    int q = t & (L - 1);
    double2 x0 = src[SL(q + (p)         * L)];
    double2 x1 = src[SL(q + (p + m)     * L)];
    double2 x2 = src[SL(q + (p + 2 * m) * L)];
    double2 x3 = src[SL(q + (p + 3 * m) * L)];
    double t0x = x0.x + x2.x, t0y = x0.y + x2.y;
    double t1x = x0.x - x2.x, t1y = x0.y - x2.y;
    double t2x = x1.x + x3.x, t2y = x1.y + x3.y;
    double t3x = x1.x - x3.x, t3y = x1.y - x3.y;
    double y0x = t0x + t2x, y0y = t0y + t2y;
    double y2x = t0x - t2x, y2y = t0y - t2y;
    double y1x, y1y, y3x, y3y;
    if (INV) {               // y1 = t1 + i t3 ; y3 = t1 - i t3
      y1x = t1x - t3y; y1y = t1y + t3x;
      y3x = t1x + t3y; y3y = t1y - t3x;
    } else {                 // y1 = t1 - i t3 ; y3 = t1 + i t3
      y1x = t1x + t3y; y1y = t1y - t3x;
      y3x = t1x - t3y; y3y = t1y + t3x;
    }
    int base = p << (2 * s);             // twiddle index unit: r*p*4^s
    double2 w1 = tw512[base];
    double2 w2 = tw512[2 * base];
    double2 w3 = tw512[3 * base];
    double w1y = INV ? -w1.y : w1.y;
    double w2y = INV ? -w2.y : w2.y;
    double w3y = INV ? -w3.y : w3.y;
    double2 o0; o0.x = y0x; o0.y = y0y;
    double2 o1; o1.x = y1x * w1.x - y1y * w1y; o1.y = y1x * w1y + y1y * w1.x;
    double2 o2; o2.x = y2x * w2.x - y2y * w2y; o2.y = y2x * w2y + y2y * w2.x;
    double2 o3; o3.x = y3x * w3.x - y3y * w3y; o3.y = y3x * w3y + y3y * w3.x;
    int ob = q + (4 * p) * L;
    dst[SL(ob)]         = o0;
    dst[SL(ob + L)]     = o1;
    dst[SL(ob + 2 * L)] = o2;
    dst[SL(ob + 3 * L)] = o3;
    __syncthreads();
    double2* tmp = src; src = dst; dst = tmp;
  }
  // final radix-2 stage (no twiddle)
  #pragma unroll
  for (int r = 0; r < 2; ++r) {
    int q = t + (r << 7);
    double2 x0 = src[SL(q)];
    double2 x1 = src[SL(q + 256)];
    double2 e; e.x = x0.x + x1.x; e.y = x0.y + x1.y;
    double2 o; o.x = x0.x - x1.x; o.y = x0.y - x1.y;
    dst[SL(q)]       = e;
    dst[SL(q + 256)] = o;
  }
  __syncthreads();
  return dst;
}

// ---------------- initial ISTFT: irfft(1024) of mag*ang(global) via ifft(512), *win ----------------
__global__ __launch_bounds__(128) void k_istft(const float* __restrict__ mag, const float2* __restrict__ ang,
                                               float* __restrict__ frames,
                                               const double2* __restrict__ tw512,
                                               const double2* __restrict__ twh,
                                               const float* __restrict__ win)
{
  __shared__ double2 A[LDSN];
  __shared__ double2 B[LDSN];
  int bf = blockIdx.x;          // b*512 + f
  int t = threadIdx.x;
  const float*  mrow = mag + bf * NFREQ;
  const float2* arow = ang + bf * NFREQ;
  for (int k = t; k < 512; k += 128) {
    float m1 = mrow[k];       float2 a1 = arow[k];
    int k2 = 512 - k;
    float m2 = mrow[k2];      float2 a2 = arow[k2];
    float S1x = __fmul_rn(m1, a1.x), S1y = __fmul_rn(m1, a1.y);
    float S2x = __fmul_rn(m2, a2.x), S2y = __fmul_rn(m2, a2.y);
    double2 Z;
    if (k == 0) {
      double e = 0.5 * ((double)S1x + (double)S2x);
      double d = 0.5 * ((double)S1x - (double)S2x);
      Z.x = e; Z.y = d;
    } else {
      double Xex = 0.5 * ((double)S1x + (double)S2x);
      double Xey = 0.5 * ((double)S1y - (double)S2y);
      double Dx  = 0.5 * ((double)S1x - (double)S2x);
      double Dy  = 0.5 * ((double)S1y + (double)S2y);
      double2 w = twh[k];                  // e^{-2pi i k/1024}
      double ux = w.x * Dx + w.y * Dy;     // conj(w)*D
      double uy = w.x * Dy - w.y * Dx;
      Z.x = Xex - uy;
      Z.y = Xey + ux;
    }
    A[SL(k)] = Z;
  }
  __syncthreads();
  double2* R = fft512d<true>(A, B, tw512, t);
  float* frow = frames + bf * NFFT;
  for (int m = t; m < 512; m += 128) {
    double2 z = R[SL(m)];
    float xr = (float)(z.x * (1.0 / 512.0));
    float xi = (float)(z.y * (1.0 / 512.0));
    frow[2 * m]     = __fmul_rn(xr, win[2 * m]);
    frow[2 * m + 1] = __fmul_rn(xi, win[2 * m + 1]);
  }
}

// f32 OLA sample at wsq-coordinate j
__device__ __forceinline__ float sig_sample(const float* __restrict__ fb, const float* __restrict__ wsq, int j)
{
  int gmax = j >> 8; if (gmax > NW - 1) gmax = NW - 1;
  int gmin = (j >= NFFT) ? ((j - (NFFT - 1) + 255) >> 8) : 0;
  float acc = 0.f;
  for (int g = gmin; g <= gmax; ++g)
    acc = __fadd_rn(acc, fb[g * NFFT + (j - (g << 8))]);
  float wv = wsq[j];
  return __fdiv_rn(acc, wv > 1e-11f ? wv : 1.0f);
}

// ---------------- per-iteration: OLA + reflect-pad -> xp[b][0..TOTAL_LEN) ----------------
__global__ __launch_bounds__(256) void k_sig(const float* __restrict__ frames, const float* __restrict__ wsq,
                                             float* __restrict__ xp)
{
  int idx = blockIdx.x * 256 + threadIdx.x;   // < BATCH*TOTAL_LEN
  int b = idx / TOTAL_LEN;
  int j = idx - b * TOTAL_LEN;
  int n = j - 512;
  if (n < 0) n = -n;
  if (n >= SIGLEN) n = 2 * SIGLEN - 2 - n;
  xp[idx] = sig_sample(frames + b * (NW * NFFT), wsq, n + 512);
}

// ---------------- FUSED: stft_it (+ phase update in LDS) + istft_{it+1} ----------------
__global__ __launch_bounds__(128) void k_fused(const float* __restrict__ xp,
                                               const float* __restrict__ win,
                                               const double2* __restrict__ tw512,
                                               const double2* __restrict__ twh,
                                               const float* __restrict__ mag,
                                               float2* __restrict__ tprev,
                                               float* __restrict__ frames)
{
  __shared__ double2 A[LDSN];
  __shared__ double2 B[LDSN];
  __shared__ float2 angL[NFREQ];
  int bf = blockIdx.x;
  int b = bf >> 9;
  int f = bf & (NW - 1);
  int t = threadIdx.x;

  // ---- forward: pack two real samples per complex point ----
  const float* xrow = xp + b * TOTAL_LEN + f * HOP;
  for (int m = t; m < 512; m += 128) {
    float s0 = __fmul_rn(xrow[2 * m],     win[2 * m]);
    float s1 = __fmul_rn(xrow[2 * m + 1], win[2 * m + 1]);
    double2 z; z.x = (double)s0; z.y = (double)s1;
    A[SL(m)] = z;
  }
  __syncthreads();
  double2* R = fft512d<false>(A, B, tw512, t);   // result in B; A free

  // ---- unpack rfft bins + momentum phase update (all f32 boundary ops) ----
  float2* prow = tprev + bf * NFREQ;
  const float cf = (float)(0.99 / 1.99);
  for (int k = t; k < NFREQ; k += 128) {
    double rx, ry;
    if (k == 0)        { rx = R[SL(0)].x + R[SL(0)].y; ry = 0.0; }
    else if (k == 512) { rx = R[SL(0)].x - R[SL(0)].y; ry = 0.0; }
    else {
      double2 Zk = R[SL(k)];
      double2 Zc = R[SL(512 - k)];
      double Xex = 0.5 * (Zk.x + Zc.x);
      double Xey = 0.5 * (Zk.y - Zc.y);
      double Gx  = 0.5 * (Zk.x - Zc.x);
      double Gy  = 0.5 * (Zk.y + Zc.y);
      double Xox = Gy, Xoy = -Gx;          // Xo = -i*G
      double2 w = twh[k];
      rx = Xex + (w.x * Xox - w.y * Xoy);
      ry = Xey + (w.x * Xoy + w.y * Xox);
    }
    float rxf = (float)rx, ryf = (float)ry;  // rfft quantized to c64
    float2 pv = prow[k];
    float ax = __fsub_rn(rxf, __fmul_rn(pv.x, cf));
    float ay = __fsub_rn(ryf, __fmul_rn(pv.y, cf));
    double dx = (double)ax, dy = (double)ay;
    float d = (float)sqrt(dx * dx + dy * dy);   // np.abs(c64) = hypotf
    float d2 = __fadd_rn(d, 1e-16f);
    float inv = __fdiv_rn(1.0f, d2);
    angL[k] = make_float2(__fmul_rn(ax, inv), __fmul_rn(ay, inv));
    prow[k] = make_float2(rxf, ryf);
  }
  __syncthreads();   // angL complete (pack reads angL[512-k] across threads)

  // ---- inverse: Hermitian pack mag*angL into A ----
  const float* mrow = mag + bf * NFREQ;
  for (int k = t; k < 512; k += 128) {
    float m1 = mrow[k];       float2 a1 = angL[k];
    int k2 = 512 - k;
    float m2 = mrow[k2];      float2 a2 = angL[k2];
    float S1x = __fmul_rn(m1, a1.x), S1y = __fmul_rn(m1, a1.y);
    float S2x = __fmul_rn(m2, a2.x), S2y = __fmul_rn(m2, a2.y);
    double2 Z;
    if (k == 0) {
      double e = 0.5 * ((double)S1x + (double)S2x);
      double d = 0.5 * ((double)S1x - (double)S2x);
      Z.x = e; Z.y = d;
    } else {
      double Xex = 0.5 * ((double)S1x + (double)S2x);
      double Xey = 0.5 * ((double)S1y - (double)S2y);
      double Dx  = 0.5 * ((double)S1x - (double)S2x);
      double Dy  = 0.5 * ((double)S1y + (double)S2y);
      double2 w = twh[k];
      double ux = w.x * Dx + w.y * Dy;
      double uy = w.x * Dy - w.y * Dx;
      Z.x = Xex - uy;
      Z.y = Xey + ux;
    }
    A[SL(k)] = Z;
  }
  __syncthreads();
  double2* R2 = fft512d<true>(A, B, tw512, t);
  float* frow = frames + bf * NFFT;
  for (int m = t; m < 512; m += 128) {
    double2 z = R2[SL(m)];
    float xr = (float)(z.x * (1.0 / 512.0));
    float xi = (float)(z.y * (1.0 / 512.0));
    frow[2 * m]     = __fmul_rn(xr, win[2 * m]);
    frow[2 * m + 1] = __fmul_rn(xi, win[2 * m + 1]);
  }
}

// ---------------- final OLA -> audio f32 (pure streaming, no reduction) ----------------
__global__ __launch_bounds__(256) void k_ola(const float* __restrict__ frames, const float* __restrict__ wsq,
                                             float* __restrict__ audio)
{
  int idx = blockIdx.x * 256 + threadIdx.x;  // < BATCH*NSAMP
  int b  = idx >> 17;
  int nn = idx & (NSAMP - 1);
  float v = 0.f;
  if (nn < SIGLEN)
    v = sig_sample(frames + b * (NW * NFFT), wsq, nn + 512);
  audio[idx] = v;
}

// ---------------- per-batch |max|, two-stage (no atomics; fmax associative -> bit-exact) ----------------
constexpr int MAXCHUNK = 64;     // blocks per batch in stage 1; 2048 elems per block

__global__ __launch_bounds__(256) void k_max1(const float* __restrict__ audio, float* __restrict__ partial)
{
  int blk = blockIdx.x;                 // b*MAXCHUNK + c
  int b = blk / MAXCHUNK;
  int c = blk - b * MAXCHUNK;
  const float* arow = audio + b * NSAMP + c * (NSAMP / MAXCHUNK);
  float m = 0.f;
  for (int i = threadIdx.x; i < NSAMP / MAXCHUNK; i += 256)
    m = fmaxf(m, fabsf(arow[i]));
  __shared__ float red[256];
  red[threadIdx.x] = m;
  __syncthreads();
  for (int s = 128; s > 0; s >>= 1) {
    if (threadIdx.x < s) red[threadIdx.x] = fmaxf(red[threadIdx.x], red[threadIdx.x + s]);
    __syncthreads();
  }
  if (threadIdx.x == 0) partial[blk] = red[0];
}

__global__ __launch_bounds__(64) void k_max2(const float* __restrict__ partial, float* __restrict__ maxbuf)
{
  int b = blockIdx.x;
  __shared__ float red[64];
  red[threadIdx.x] = partial[b * MAXCHUNK + threadIdx.x];
  __syncthreads();
  for (int s = 32; s > 0; s >>= 1) {
    if (threadIdx.x < s) red[threadIdx.x] = fmaxf(red[threadIdx.x], red[threadIdx.x + s]);
    __syncthreads();
  }
  if (threadIdx.x == 0) maxbuf[b] = red[0];
}

__global__ __launch_bounds__(256) void k_norm(const float* __restrict__ audio, const float* __restrict__ maxbuf,
                                              float* __restrict__ out)
{
  int idx = blockIdx.x * 256 + threadIdx.x;
  int b = idx >> 17;
  float m = fmaxf(maxbuf[b], 1e-8f);
  out[idx] = __fmul_rn(__fdiv_rn(audio[idx], m), 0.9f);
}

extern "C" void kernel_launch(void* const* d_in, const int* in_sizes, int n_in,
                              void* d_out, int out_size, void* d_ws, size_t ws_size,
                              hipStream_t stream)
{
  const float* params = (const float*)d_in[0];
  float* out   = (float*)d_out;
  float* audio_out = out;                   // BATCH*NSAMP
  float* fs        = out + BATCH * NSAMP;   // BATCH*FH*FW (full_spec output)

  // workspace layout (16B-aligned first)
  double2* tw512  = (double2*)d_ws;                        // 512
  double2* twh    = tw512 + 512;                           // 512
  float2*  ang    = (float2*)(twh + 512);                  // NMAG c64 (initial phases only)
  float2*  tprev  = ang + NMAG;                            // NMAG c64
  float*   frames = (float*)(tprev + NMAG);                // BATCH*NW*NFFT f32
  float*   mag    = frames + BATCH * NW * NFFT;            // NMAG f32
  float*   xp     = mag + NMAG;                            // BATCH*TOTAL_LEN f32
  float*   win    = xp + BATCH * TOTAL_LEN;                // NFFT
  float*   wsq    = win + NFFT;                            // TOTAL_LEN
  float*   audio32= wsq + TOTAL_LEN;                       // BATCH*NSAMP
  float*   maxbuf = audio32 + BATCH * NSAMP;               // BATCH
  float*   partial= maxbuf + BATCH;                        // BATCH*MAXCHUNK

  k_init<<<512, 256, 0, stream>>>(win, tw512, twh, wsq, tprev);
  k_fullspec<<<(BATCH * FH * FW) / 256, 256, 0, stream>>>(params, fs);
  k_mag<<<(NMAG + 255) / 256, 256, 0, stream>>>(params, mag);
  k_phase<<<(NMAG + 255) / 256, 256, 0, stream>>>(ang);

  // istft0 with initial phases, then 32x [OLA->xp ; fused stft+update+istft]
  k_istft<<<BATCH * NW, 128, 0, stream>>>(mag, (const float2*)ang, frames, tw512, twh, win);
  for (int it = 0; it < NITER; ++it) {
    k_sig<<<(BATCH * TOTAL_LEN) / 256, 256, 0, stream>>>(frames, wsq, xp);
    k_fused<<<BATCH * NW, 128, 0, stream>>>(xp, win, tw512, twh, mag, tprev, frames);
  }
  k_ola<<<(BATCH * NSAMP) / 256, 256, 0, stream>>>(frames, wsq, audio32);
  k_max1<<<BATCH * MAXCHUNK, 256, 0, stream>>>(audio32, partial);
  k_max2<<<BATCH, 64, 0, stream>>>(partial, maxbuf);
  k_norm<<<(BATCH * NSAMP) / 256, 256, 0, stream>>>(audio32, maxbuf, audio_out);
}